// Round 7
// baseline (354.392 us; speedup 1.0000x reference)
//
#include <hip/hip_runtime.h>
#include <stdint.h>

#define D_MODEL 1024
#define NH 16
#define DH 64
#define TSEQ 2048
#define BATCH 4
#define MTOT (BATCH*TSEQ)
#define NQ (MTOT*D_MODEL)      // elements in Q/K/VT/AO and in x
#define WSZ (D_MODEL*D_MODEL)  // elements in each weight matrix
// SCALE * log2(e), pre-folded into Q at the qkv epilogue
#define QSCALE 0.18033688f

typedef __attribute__((ext_vector_type(8))) short bf16x8;
typedef __attribute__((ext_vector_type(8))) unsigned short u16x8;
typedef __attribute__((ext_vector_type(4))) float f32x4;
typedef __attribute__((ext_vector_type(2))) float f32x2;
typedef unsigned short u16;
typedef unsigned int u32;

__device__ __forceinline__ void gl_lds16(const void* g, void* l) {
  __builtin_amdgcn_global_load_lds(
      (__attribute__((address_space(1))) void*)g,
      (__attribute__((address_space(3))) void*)l, 16, 0, 0);
}
__device__ __forceinline__ u16 f2bf(float f) {
  u32 u = __builtin_bit_cast(u32, f);
  u = u + 0x7fffu + ((u >> 16) & 1u);
  return (u16)(u >> 16);
}
__device__ __forceinline__ float bf2f(u16 b) {
  u32 u = ((u32)b) << 16;
  return __builtin_bit_cast(float, u);
}
// pack hi16(fa+0x8000)<<16 | hi16(fb+0x8000); low word = fb
__device__ __forceinline__ u32 pack2bf(float fb, float fa) {
  const u32 ua = __builtin_bit_cast(u32, fa) + 0x8000u;
  const u32 ub = __builtin_bit_cast(u32, fb) + 0x8000u;
  return __builtin_amdgcn_perm(ua, ub, 0x07060302u);
}

// ---------------------------------------------------------------------------
// Kernel 0: input dtype detection (1 = bf16, 0 = fp32). Round-4 verified.
// ---------------------------------------------------------------------------
__global__ __launch_bounds__(256) void detect_dtype(
    const u32* __restrict__ wq_raw, int* __restrict__ flag)
{
  __shared__ int cnt;
  if (threadIdx.x == 0) cnt = 0;
  __syncthreads();
  int c = 0;
  for (int i = threadIdx.x; i < 2048; i += 256) {
    const u32 e = (wq_raw[i] >> 7) & 0xFFu;
    if (e >= 90u && e <= 126u) ++c;
  }
  atomicAdd(&cnt, c);
  __syncthreads();
  if (threadIdx.x == 0) *flag = (cnt > 1024) ? 1 : 0;
}

// ---------------------------------------------------------------------------
// Kernel 0b: convert inputs to bf16. seg 0 = x -> d_out low half (fp32 only),
// 1..4 = Wq,Wk,Wv,Wo -> d_ws.
// ---------------------------------------------------------------------------
__global__ __launch_bounds__(256) void convert_inputs(
    const void* __restrict__ x, const void* __restrict__ wq,
    const void* __restrict__ wk, const void* __restrict__ wv,
    const void* __restrict__ wo,
    u16* __restrict__ xb, u16* __restrict__ wqb, u16* __restrict__ wkb,
    u16* __restrict__ wvb, u16* __restrict__ wob,
    const int* __restrict__ flag_p)
{
  const int flag = *flag_p;
  const int seg = blockIdx.y;
  const void* src; u16* dst; int n;
  switch (seg) {
    case 0:  src = x;  dst = xb;  n = NQ;  break;
    case 1:  src = wq; dst = wqb; n = WSZ; break;
    case 2:  src = wk; dst = wkb; n = WSZ; break;
    case 3:  src = wv; dst = wvb; n = WSZ; break;
    default: src = wo; dst = wob; n = WSZ; break;
  }
  if (flag && seg == 0) return;
  const int idx = (blockIdx.x * 256 + threadIdx.x) * 8;
  if (idx >= n) return;
  if (flag) {
    *(u16x8*)(dst + idx) = *(const u16x8*)((const u16*)src + idx);
  } else {
    const float4 f0 = *(const float4*)((const float*)src + idx);
    const float4 f1 = *(const float4*)((const float*)src + idx + 4);
    union { u16 s[8]; u16x8 v; } u;
    u.s[0] = f2bf(f0.x); u.s[1] = f2bf(f0.y); u.s[2] = f2bf(f0.z); u.s[3] = f2bf(f0.w);
    u.s[4] = f2bf(f1.x); u.s[5] = f2bf(f1.y); u.s[6] = f2bf(f1.z); u.s[7] = f2bf(f1.w);
    *(u16x8*)(dst + idx) = u.v;
  }
}

// ---------------------------------------------------------------------------
// Kernel 1: QKV projection (m97 structure: gl_lds width-16 staging).
// z=0 -> Q^T [B,H,64,T] (pre-scaled by QSCALE, vectorized store);
// z=1 -> K  [B,H,T,64] (scalar store; flash needs d-contiguous for gl_lds);
// z=2 -> V^T [B,H,64,T] (vectorized store).
// ---------------------------------------------------------------------------
__global__ __launch_bounds__(256) void qkv_gemm(
    const int* __restrict__ flag_p, const u16* __restrict__ x_raw,
    u16* __restrict__ dout,
    const u16* __restrict__ Wq, const u16* __restrict__ Wk,
    const u16* __restrict__ Wv,
    u16* __restrict__ Ko, u16* __restrict__ VTo)
{
  __shared__ __align__(16) u16 As[128 * 32];
  __shared__ __align__(16) u16 Bs[128 * 32];
  const int flag = *flag_p;
  const u16* __restrict__ X = flag ? x_raw : dout;  // converted x in dout low
  u16* __restrict__ QTo = flag ? dout : dout + NQ;
  const int t = threadIdx.x;
  const int z = blockIdx.z;
  const u16* __restrict__ W = (z == 0) ? Wq : (z == 1) ? Wk : Wv;
  const int m0 = blockIdx.x * 128;
  const int n0 = blockIdx.y * 128;
  const int wave = t >> 6, lane = t & 63;
  const int wm = (wave >> 1) * 64, wn = (wave & 1) * 64;
  const int lr = lane & 15, kg = (lane >> 4) * 8;

  const int srow0 = t >> 2, skc = (t & 3) * 8;
  const int srow1 = srow0 + 64;
  const u16* a0 = X + (size_t)(m0 + srow0) * D_MODEL + skc;
  const u16* a1 = X + (size_t)(m0 + srow1) * D_MODEL + skc;
  const u16* b0 = W + (size_t)(n0 + srow0) * D_MODEL + skc;
  const u16* b1 = W + (size_t)(n0 + srow1) * D_MODEL + skc;

  f32x4 acc[4][4] = {};

  for (int kt = 0; kt < D_MODEL / 32; ++kt) {
    gl_lds16(a0, &As[t * 8]);
    gl_lds16(a1, &As[(t + 256) * 8]);
    gl_lds16(b0, &Bs[t * 8]);
    gl_lds16(b1, &Bs[(t + 256) * 8]);
    a0 += 32; a1 += 32; b0 += 32; b1 += 32;
    __syncthreads();
    bf16x8 af[4], bfr[4];
#pragma unroll
    for (int i = 0; i < 4; ++i)
      af[i] = *(const bf16x8*)&As[(wm + i * 16 + lr) * 32 + kg];
#pragma unroll
    for (int j = 0; j < 4; ++j)
      bfr[j] = *(const bf16x8*)&Bs[(wn + j * 16 + lr) * 32 + kg];
#pragma unroll
    for (int i = 0; i < 4; ++i)
#pragma unroll
      for (int j = 0; j < 4; ++j)
        acc[i][j] = __builtin_amdgcn_mfma_f32_16x16x32_bf16(af[i], bfr[j], acc[i][j], 0, 0, 0);
    __syncthreads();
  }

  // C/D layout: col = lane&15, row = (lane>>4)*4 + reg
  const int bidx = m0 >> 11;
  if (z == 1) {
    // K: [B,H,T,64], scalar stores (d-contiguous rows for flash staging)
#pragma unroll
    for (int i = 0; i < 4; ++i) {
      const int rowg = m0 + wm + i * 16 + ((lane >> 4) << 2);
      const int tq = rowg & (TSEQ - 1);
#pragma unroll
      for (int j = 0; j < 4; ++j) {
        const int colg = n0 + wn + j * 16 + lr;
        const int h = colg >> 6, d = colg & 63;
        u16* dst = Ko + ((size_t)(bidx * NH + h) * TSEQ + tq) * DH + d;
#pragma unroll
        for (int r = 0; r < 4; ++r)
          dst[(size_t)r * DH] = f2bf(acc[i][j][r]);
      }
    }
  } else {
    // Q^T (scaled) and V^T: [B,H,64,T], vectorized 8B stores along t
    u16* O = (z == 0) ? QTo : VTo;
    const float sc = (z == 0) ? QSCALE : 1.0f;
#pragma unroll
    for (int i = 0; i < 4; ++i) {
      const int rowg = m0 + wm + i * 16 + ((lane >> 4) << 2);
      const int tq = rowg & (TSEQ - 1);  // multiple of 4 -> 8B aligned
#pragma unroll
      for (int j = 0; j < 4; ++j) {
        const int colg = n0 + wn + j * 16 + lr;
        const int h = colg >> 6, d = colg & 63;
        union { u16 s[4]; uint2 v; } u;
#pragma unroll
        for (int r = 0; r < 4; ++r) u.s[r] = f2bf(acc[i][j][r] * sc);
        *(uint2*)&O[((size_t)(bidx * NH + h) * DH + d) * TSEQ + tq] = u.v;
      }
    }
  }
}

// ---------------------------------------------------------------------------
// Kernel 2: flash attention, 128 q-rows per block (2 q-fragments per wave
// sharing the staged K/V tile): 32 MFMA per barrier pair, grid = 1024 blocks
// = exactly 4/CU, LDS ~35 KB = exactly 4 blocks/CU. No-max softmax.
// ---------------------------------------------------------------------------
__global__ __launch_bounds__(256) void flash_attn(
    const int* __restrict__ flag_p, const u16* __restrict__ dout,
    const u16* __restrict__ K, const u16* __restrict__ VT,
    u16* __restrict__ AO)
{
  __shared__ __align__(16) u16 Ks[2 * 64 * 32];
  __shared__ __align__(16) u16 Vs[2 * 64 * 32];
  __shared__ __align__(16) u16 Ps[4 * 32 * 72];  // per-wave [32 q][64+8 keys]
  __shared__ float Ls[4 * 32];
  const int flag = *flag_p;
  const u16* __restrict__ QT = flag ? dout : dout + NQ;
  const int t = threadIdx.x;
  const int wave = t >> 6, lane = t & 63;
  const int lr = lane & 15, g = lane >> 4, kg = g * 8;
  const int bh = blockIdx.y;
  const int q0 = blockIdx.x * 128;
  const u16* __restrict__ QTh = QT + (size_t)bh * DH * TSEQ;  // [64 d][T]
  const u16* __restrict__ Kh = K + (size_t)bh * TSEQ * DH;
  const u16* __restrict__ Vh = VT + (size_t)bh * DH * TSEQ;

  // Two Q B-fragments per wave (q-sets A/B, 16 q each), gathered from Q^T
  // once per kernel: 32 strided scalar loads.
  const int qiA = q0 + wave * 32 + lr;
  union { u16 s[8]; bf16x8 v; } qa0, qa1, qb0, qb1;
#pragma unroll
  for (int j = 0; j < 8; ++j) {
    qa0.s[j] = QTh[(size_t)(kg + j) * TSEQ + qiA];
    qa1.s[j] = QTh[(size_t)(32 + kg + j) * TSEQ + qiA];
    qb0.s[j] = QTh[(size_t)(kg + j) * TSEQ + qiA + 16];
    qb1.s[j] = QTh[(size_t)(32 + kg + j) * TSEQ + qiA + 16];
  }
  const bf16x8 qfA0 = qa0.v, qfA1 = qa1.v, qfB0 = qb0.v, qfB1 = qb1.v;

  f32x4 accA[4] = {}, accB[4] = {};
  f32x2 lsA0 = {0.f, 0.f}, lsA1 = {0.f, 0.f};
  f32x2 lsB0 = {0.f, 0.f}, lsB1 = {0.f, 0.f};

  const int srow = t >> 2, skc = (t & 3) * 8;
  const u16* kb = Kh + (size_t)srow * DH + skc;
  const u16* vb = Vh + (size_t)srow * TSEQ + skc;
  u16* const pw  = &Ps[wave * 32 * 72];        // q-set A rows 0..15
  u16* const pwB = pw + 16 * 72;               // q-set B rows 16..31

  for (int j0 = 0; j0 < TSEQ; j0 += 64) {
    gl_lds16(kb,      &Ks[t * 8]);          // keys, d 0..31
    gl_lds16(kb + 32, &Ks[(t + 256) * 8]);  // keys, d 32..63
    gl_lds16(vb,      &Vs[t * 8]);          // [d][keys 0..31]
    gl_lds16(vb + 32, &Vs[(t + 256) * 8]);  // [d][keys 32..63]
    kb += 64 * DH; vb += 64;
    __syncthreads();

    // S^T tiles: C col = q (lr), row = key = jn*16 + g*4 + r
#pragma unroll
    for (int jn = 0; jn < 4; ++jn) {
      const bf16x8 kf0 = *(const bf16x8*)&Ks[(jn * 16 + lr) * 32 + kg];
      const bf16x8 kf1 = *(const bf16x8*)&Ks[2048 + (jn * 16 + lr) * 32 + kg];
      f32x4 sA = {}, sB = {};
      sA = __builtin_amdgcn_mfma_f32_16x16x32_bf16(kf0, qfA0, sA, 0, 0, 0);
      sA = __builtin_amdgcn_mfma_f32_16x16x32_bf16(kf1, qfA1, sA, 0, 0, 0);
      sB = __builtin_amdgcn_mfma_f32_16x16x32_bf16(kf0, qfB0, sB, 0, 0, 0);
      sB = __builtin_amdgcn_mfma_f32_16x16x32_bf16(kf1, qfB1, sB, 0, 0, 0);
      const float a0 = __builtin_exp2f(sA[0]);
      const float a1 = __builtin_exp2f(sA[1]);
      const float a2 = __builtin_exp2f(sA[2]);
      const float a3 = __builtin_exp2f(sA[3]);
      const float b0 = __builtin_exp2f(sB[0]);
      const float b1 = __builtin_exp2f(sB[1]);
      const float b2 = __builtin_exp2f(sB[2]);
      const float b3 = __builtin_exp2f(sB[3]);
      lsA0 += (f32x2){a0, a1}; lsA1 += (f32x2){a2, a3};
      lsB0 += (f32x2){b0, b1}; lsB1 += (f32x2){b2, b3};
      uint2 wA, wB;
      wA.x = pack2bf(a0, a1); wA.y = pack2bf(a2, a3);
      wB.x = pack2bf(b0, b1); wB.y = pack2bf(b2, b3);
      *(uint2*)&pw [lr * 72 + jn * 16 + g * 4] = wA;
      *(uint2*)&pwB[lr * 72 + jn * 16 + g * 4] = wB;
    }

    // PV: A = P (m=q), B = V^T rows (n=d). Same-wave DS RAW is in-order.
    const bf16x8 pfA0 = *(const bf16x8*)&pw [lr * 72 + kg];
    const bf16x8 pfA1 = *(const bf16x8*)&pw [lr * 72 + 32 + kg];
    const bf16x8 pfB0 = *(const bf16x8*)&pwB[lr * 72 + kg];
    const bf16x8 pfB1 = *(const bf16x8*)&pwB[lr * 72 + 32 + kg];
#pragma unroll
    for (int dn = 0; dn < 4; ++dn) {
      const bf16x8 vf0 = *(const bf16x8*)&Vs[(dn * 16 + lr) * 32 + kg];
      const bf16x8 vf1 = *(const bf16x8*)&Vs[2048 + (dn * 16 + lr) * 32 + kg];
      accA[dn] = __builtin_amdgcn_mfma_f32_16x16x32_bf16(pfA0, vf0, accA[dn], 0, 0, 0);
      accA[dn] = __builtin_amdgcn_mfma_f32_16x16x32_bf16(pfA1, vf1, accA[dn], 0, 0, 0);
      accB[dn] = __builtin_amdgcn_mfma_f32_16x16x32_bf16(pfB0, vf0, accB[dn], 0, 0, 0);
      accB[dn] = __builtin_amdgcn_mfma_f32_16x16x32_bf16(pfB1, vf1, accB[dn], 0, 0, 0);
    }
    __syncthreads();
  }

  // lsum reductions: lane partial covers key subset for q=lr of each set
  float lA = (lsA0[0] + lsA0[1]) + (lsA1[0] + lsA1[1]);
  lA += __shfl_xor(lA, 16, 64);
  lA += __shfl_xor(lA, 32, 64);
  float lB = (lsB0[0] + lsB0[1]) + (lsB1[0] + lsB1[1]);
  lB += __shfl_xor(lB, 16, 64);
  lB += __shfl_xor(lB, 32, 64);
  Ls[wave * 32 + lr]      = lA;  // same-value multi-write across g, benign
  Ls[wave * 32 + 16 + lr] = lB;
  __syncthreads();

  const int bb = bh >> 4, hh = bh & 15;
#pragma unroll
  for (int r = 0; r < 4; ++r) {
    const int qq = g * 4 + r;
    const float invA = 1.f / fmaxf(Ls[wave * 32 + qq], 1e-30f);
    const float invB = 1.f / fmaxf(Ls[wave * 32 + 16 + qq], 1e-30f);
    const int tiA = q0 + wave * 32 + qq;
    u16* dstA = AO + (((size_t)bb * TSEQ + tiA) * NH + hh) * DH + lr;
    u16* dstB = AO + (((size_t)bb * TSEQ + tiA + 16) * NH + hh) * DH + lr;
#pragma unroll
    for (int dn = 0; dn < 4; ++dn) {
      dstA[dn * 16] = f2bf(accA[dn][r] * invA);
      dstB[dn * 16] = f2bf(accB[dn][r] * invB);
    }
  }
}

// ---------------------------------------------------------------------------
// Kernel 3: output projection  out = AO @ Wo^T + bo  (gl_lds staging).
// ---------------------------------------------------------------------------
__global__ __launch_bounds__(256) void out_gemm(
    const int* __restrict__ flag_p,
    const u16* __restrict__ A, const u16* __restrict__ W,
    const void* __restrict__ bias_raw, void* __restrict__ outp)
{
  __shared__ __align__(16) u16 As[128 * 32];
  __shared__ __align__(16) u16 Bs[128 * 32];
  const int flag = *flag_p;
  const int t = threadIdx.x;
  const int m0 = blockIdx.x * 128;
  const int n0 = blockIdx.y * 128;
  const int wave = t >> 6, lane = t & 63;
  const int wm = (wave >> 1) * 64, wn = (wave & 1) * 64;
  const int lr = lane & 15, kg = (lane >> 4) * 8;

  const int srow0 = t >> 2, skc = (t & 3) * 8;
  const int srow1 = srow0 + 64;
  const u16* a0 = A + (size_t)(m0 + srow0) * D_MODEL + skc;
  const u16* a1 = A + (size_t)(m0 + srow1) * D_MODEL + skc;
  const u16* b0 = W + (size_t)(n0 + srow0) * D_MODEL + skc;
  const u16* b1 = W + (size_t)(n0 + srow1) * D_MODEL + skc;

  f32x4 acc[4][4] = {};

  for (int kt = 0; kt < D_MODEL / 32; ++kt) {
    gl_lds16(a0, &As[t * 8]);
    gl_lds16(a1, &As[(t + 256) * 8]);
    gl_lds16(b0, &Bs[t * 8]);
    gl_lds16(b1, &Bs[(t + 256) * 8]);
    a0 += 32; a1 += 32; b0 += 32; b1 += 32;
    __syncthreads();
    bf16x8 af[4], bfr[4];
#pragma unroll
    for (int i = 0; i < 4; ++i)
      af[i] = *(const bf16x8*)&As[(wm + i * 16 + lr) * 32 + kg];
#pragma unroll
    for (int j = 0; j < 4; ++j)
      bfr[j] = *(const bf16x8*)&Bs[(wn + j * 16 + lr) * 32 + kg];
#pragma unroll
    for (int i = 0; i < 4; ++i)
#pragma unroll
      for (int j = 0; j < 4; ++j)
        acc[i][j] = __builtin_amdgcn_mfma_f32_16x16x32_bf16(af[i], bfr[j], acc[i][j], 0, 0, 0);
    __syncthreads();
  }

#pragma unroll
  for (int j = 0; j < 4; ++j) {
    const int colg = n0 + wn + j * 16 + lr;
    const float bv = flag ? bf2f(((const u16*)bias_raw)[colg])
                          : ((const float*)bias_raw)[colg];
#pragma unroll
    for (int i = 0; i < 4; ++i) {
      const int rowg = m0 + wm + i * 16 + ((lane >> 4) << 2);
      if (flag) {
        u16* dst = (u16*)outp + (size_t)rowg * D_MODEL + colg;
#pragma unroll
        for (int r = 0; r < 4; ++r)
          dst[(size_t)r * D_MODEL] = f2bf(acc[i][j][r] + bv);
      } else {
        float* dst = (float*)outp + (size_t)rowg * D_MODEL + colg;
#pragma unroll
        for (int r = 0; r < 4; ++r)
          dst[(size_t)r * D_MODEL] = acc[i][j][r] + bv;
      }
    }
  }
}

extern "C" void kernel_launch(void* const* d_in, const int* in_sizes, int n_in,
                              void* d_out, int out_size, void* d_ws, size_t ws_size,
                              hipStream_t stream) {
  const void* x  = d_in[0];
  const void* wq = d_in[1];
  const void* wk = d_in[2];
  const void* wv = d_in[3];
  const void* wo = d_in[4];
  const void* bo = d_in[5];
  u16* dout = (u16*)d_out;

  // ws: [flag 16B][Wq][Wk][Wv][Wo bf16, 2MiB ea][K][VT][AO 16MiB ea]
  int* flag = (int*)d_ws;
  u16* wqb = (u16*)d_ws + 8;
  u16* wkb = wqb + WSZ;
  u16* wvb = wkb + WSZ;
  u16* wob = wvb + WSZ;
  u16* kk  = wob + WSZ;
  u16* vt  = kk + NQ;
  u16* ao  = vt + NQ;

  detect_dtype<<<1, 256, 0, stream>>>((const u32*)wq, flag);

  dim3 gc(NQ / (256 * 8), 5);
  convert_inputs<<<gc, dim3(256), 0, stream>>>(
      x, wq, wk, wv, wo, dout, wqb, wkb, wvb, wob, flag);

  dim3 g1(MTOT / 128, D_MODEL / 128, 3);
  qkv_gemm<<<g1, dim3(256), 0, stream>>>(
      flag, (const u16*)x, dout, wqb, wkb, wvb, kk, vt);

  dim3 g2(TSEQ / 128, BATCH * NH, 1);
  flash_attn<<<g2, dim3(256), 0, stream>>>(flag, dout, kk, vt, ao);

  dim3 g3(MTOT / 128, D_MODEL / 128, 1);
  out_gemm<<<g3, dim3(256), 0, stream>>>(flag, ao, wob, bo, d_out);
}

// Round 8
// 333.200 us; speedup vs baseline: 1.0636x; 1.0636x over previous
//
#include <hip/hip_runtime.h>
#include <stdint.h>

#define D_MODEL 1024
#define NH 16
#define DH 64
#define TSEQ 2048
#define BATCH 4
#define MTOT (BATCH*TSEQ)
#define NQ (MTOT*D_MODEL)      // elements in Q/K/VT/AO and in x
#define WSZ (D_MODEL*D_MODEL)  // elements in each weight matrix
// SCALE * log2(e), pre-folded into Q at the qkv epilogue
#define QSCALE 0.18033688f

typedef __attribute__((ext_vector_type(8))) short bf16x8;
typedef __attribute__((ext_vector_type(8))) unsigned short u16x8;
typedef __attribute__((ext_vector_type(4))) float f32x4;
typedef __attribute__((ext_vector_type(2))) float f32x2;
typedef unsigned short u16;
typedef unsigned int u32;

__device__ __forceinline__ void gl_lds16(const void* g, void* l) {
  __builtin_amdgcn_global_load_lds(
      (__attribute__((address_space(1))) void*)g,
      (__attribute__((address_space(3))) void*)l, 16, 0, 0);
}
__device__ __forceinline__ u16 f2bf(float f) {
  u32 u = __builtin_bit_cast(u32, f);
  u = u + 0x7fffu + ((u >> 16) & 1u);
  return (u16)(u >> 16);
}
__device__ __forceinline__ float bf2f(u16 b) {
  u32 u = ((u32)b) << 16;
  return __builtin_bit_cast(float, u);
}
// pack hi16(fa+0x8000)<<16 | hi16(fb+0x8000); low word = fb
__device__ __forceinline__ u32 pack2bf(float fb, float fa) {
  const u32 ua = __builtin_bit_cast(u32, fa) + 0x8000u;
  const u32 ub = __builtin_bit_cast(u32, fb) + 0x8000u;
  return __builtin_amdgcn_perm(ua, ub, 0x07060302u);
}

// ---------------------------------------------------------------------------
// Kernel 0: input dtype detection (1 = bf16, 0 = fp32). Round-4 verified.
// ---------------------------------------------------------------------------
__global__ __launch_bounds__(256) void detect_dtype(
    const u32* __restrict__ wq_raw, int* __restrict__ flag)
{
  __shared__ int cnt;
  if (threadIdx.x == 0) cnt = 0;
  __syncthreads();
  int c = 0;
  for (int i = threadIdx.x; i < 2048; i += 256) {
    const u32 e = (wq_raw[i] >> 7) & 0xFFu;
    if (e >= 90u && e <= 126u) ++c;
  }
  atomicAdd(&cnt, c);
  __syncthreads();
  if (threadIdx.x == 0) *flag = (cnt > 1024) ? 1 : 0;
}

// ---------------------------------------------------------------------------
// Kernel 0b: convert inputs to bf16. seg 0 = x -> d_out low half (fp32 only),
// 1..4 = Wq,Wk,Wv,Wo -> d_ws.
// ---------------------------------------------------------------------------
__global__ __launch_bounds__(256) void convert_inputs(
    const void* __restrict__ x, const void* __restrict__ wq,
    const void* __restrict__ wk, const void* __restrict__ wv,
    const void* __restrict__ wo,
    u16* __restrict__ xb, u16* __restrict__ wqb, u16* __restrict__ wkb,
    u16* __restrict__ wvb, u16* __restrict__ wob,
    const int* __restrict__ flag_p)
{
  const int flag = *flag_p;
  const int seg = blockIdx.y;
  const void* src; u16* dst; int n;
  switch (seg) {
    case 0:  src = x;  dst = xb;  n = NQ;  break;
    case 1:  src = wq; dst = wqb; n = WSZ; break;
    case 2:  src = wk; dst = wkb; n = WSZ; break;
    case 3:  src = wv; dst = wvb; n = WSZ; break;
    default: src = wo; dst = wob; n = WSZ; break;
  }
  if (flag && seg == 0) return;
  const int idx = (blockIdx.x * 256 + threadIdx.x) * 8;
  if (idx >= n) return;
  if (flag) {
    *(u16x8*)(dst + idx) = *(const u16x8*)((const u16*)src + idx);
  } else {
    const float4 f0 = *(const float4*)((const float*)src + idx);
    const float4 f1 = *(const float4*)((const float*)src + idx + 4);
    union { u16 s[8]; u16x8 v; } u;
    u.s[0] = f2bf(f0.x); u.s[1] = f2bf(f0.y); u.s[2] = f2bf(f0.z); u.s[3] = f2bf(f0.w);
    u.s[4] = f2bf(f1.x); u.s[5] = f2bf(f1.y); u.s[6] = f2bf(f1.z); u.s[7] = f2bf(f1.w);
    *(u16x8*)(dst + idx) = u.v;
  }
}

// ---------------------------------------------------------------------------
// Kernel 1: QKV projection. BK=64 via TWO BK=32 buffers per barrier-pair
// (keeps conflict-free 32-col layout + gl_lds contiguity; 32 KB LDS).
// z=0 -> Q^T [B,H,64,T] (pre-scaled); z=1 -> K [B,H,T,64]; z=2 -> V^T.
// ---------------------------------------------------------------------------
__global__ __launch_bounds__(256) void qkv_gemm(
    const int* __restrict__ flag_p, const u16* __restrict__ x_raw,
    u16* __restrict__ dout,
    const u16* __restrict__ Wq, const u16* __restrict__ Wk,
    const u16* __restrict__ Wv,
    u16* __restrict__ Ko, u16* __restrict__ VTo)
{
  __shared__ __align__(16) u16 As[2 * 128 * 32];
  __shared__ __align__(16) u16 Bs[2 * 128 * 32];
  const int flag = *flag_p;
  const u16* __restrict__ X = flag ? x_raw : dout;  // converted x in dout low
  u16* __restrict__ QTo = flag ? dout : dout + NQ;
  const int t = threadIdx.x;
  const int z = blockIdx.z;
  const u16* __restrict__ W = (z == 0) ? Wq : (z == 1) ? Wk : Wv;
  const int m0 = blockIdx.x * 128;
  const int n0 = blockIdx.y * 128;
  const int wave = t >> 6, lane = t & 63;
  const int wm = (wave >> 1) * 64, wn = (wave & 1) * 64;
  const int lr = lane & 15, kg = (lane >> 4) * 8;

  const int srow0 = t >> 2, skc = (t & 3) * 8;
  const int srow1 = srow0 + 64;
  const u16* a0 = X + (size_t)(m0 + srow0) * D_MODEL + skc;
  const u16* a1 = X + (size_t)(m0 + srow1) * D_MODEL + skc;
  const u16* b0 = W + (size_t)(n0 + srow0) * D_MODEL + skc;
  const u16* b1 = W + (size_t)(n0 + srow1) * D_MODEL + skc;

  f32x4 acc[4][4] = {};

  for (int kt = 0; kt < D_MODEL / 64; ++kt) {
    gl_lds16(a0,      &As[t * 8]);
    gl_lds16(a1,      &As[(t + 256) * 8]);
    gl_lds16(a0 + 32, &As[4096 + t * 8]);
    gl_lds16(a1 + 32, &As[4096 + (t + 256) * 8]);
    gl_lds16(b0,      &Bs[t * 8]);
    gl_lds16(b1,      &Bs[(t + 256) * 8]);
    gl_lds16(b0 + 32, &Bs[4096 + t * 8]);
    gl_lds16(b1 + 32, &Bs[4096 + (t + 256) * 8]);
    a0 += 64; a1 += 64; b0 += 64; b1 += 64;
    __syncthreads();
#pragma unroll
    for (int h = 0; h < 2; ++h) {
      bf16x8 af[4], bfr[4];
#pragma unroll
      for (int i = 0; i < 4; ++i)
        af[i] = *(const bf16x8*)&As[h * 4096 + (wm + i * 16 + lr) * 32 + kg];
#pragma unroll
      for (int j = 0; j < 4; ++j)
        bfr[j] = *(const bf16x8*)&Bs[h * 4096 + (wn + j * 16 + lr) * 32 + kg];
#pragma unroll
      for (int i = 0; i < 4; ++i)
#pragma unroll
        for (int j = 0; j < 4; ++j)
          acc[i][j] = __builtin_amdgcn_mfma_f32_16x16x32_bf16(af[i], bfr[j], acc[i][j], 0, 0, 0);
    }
    __syncthreads();
  }

  // C/D layout: col = lane&15, row = (lane>>4)*4 + reg
  const int bidx = m0 >> 11;
  if (z == 1) {
    // K: [B,H,T,64], scalar stores (d-contiguous rows for flash staging)
#pragma unroll
    for (int i = 0; i < 4; ++i) {
      const int rowg = m0 + wm + i * 16 + ((lane >> 4) << 2);
      const int tq = rowg & (TSEQ - 1);
#pragma unroll
      for (int j = 0; j < 4; ++j) {
        const int colg = n0 + wn + j * 16 + lr;
        const int h = colg >> 6, d = colg & 63;
        u16* dst = Ko + ((size_t)(bidx * NH + h) * TSEQ + tq) * DH + d;
#pragma unroll
        for (int r = 0; r < 4; ++r)
          dst[(size_t)r * DH] = f2bf(acc[i][j][r]);
      }
    }
  } else {
    // Q^T (scaled) and V^T: [B,H,64,T], vectorized 8B stores along t
    u16* O = (z == 0) ? QTo : VTo;
    const float sc = (z == 0) ? QSCALE : 1.0f;
#pragma unroll
    for (int i = 0; i < 4; ++i) {
      const int rowg = m0 + wm + i * 16 + ((lane >> 4) << 2);
      const int tq = rowg & (TSEQ - 1);  // multiple of 4 -> 8B aligned
#pragma unroll
      for (int j = 0; j < 4; ++j) {
        const int colg = n0 + wn + j * 16 + lr;
        const int h = colg >> 6, d = colg & 63;
        union { u16 s[4]; uint2 v; } u;
#pragma unroll
        for (int r = 0; r < 4; ++r) u.s[r] = f2bf(acc[i][j][r] * sc);
        *(uint2*)&O[((size_t)(bidx * NH + h) * DH + d) * TSEQ + tq] = u.v;
      }
    }
  }
}

// ---------------------------------------------------------------------------
// Kernel 2: flash attention, 128 q-rows per block, no-max softmax.
// XCD-locality: grid = (64 bh, 16 qblk) so linear id % 8 == bh % 8 -> all 16
// q-blocks of one (b,h) share an XCD; its K/V slice (512 KB) L2-resident,
// 8 slices/XCD = 4 MiB = L2 size.
// ---------------------------------------------------------------------------
__global__ __launch_bounds__(256) void flash_attn(
    const int* __restrict__ flag_p, const u16* __restrict__ dout,
    const u16* __restrict__ K, const u16* __restrict__ VT,
    u16* __restrict__ AO)
{
  __shared__ __align__(16) u16 Ks[2 * 64 * 32];
  __shared__ __align__(16) u16 Vs[2 * 64 * 32];
  __shared__ __align__(16) u16 Ps[4 * 32 * 72];  // per-wave [32 q][64+8 keys]
  __shared__ float Ls[4 * 32];
  const int flag = *flag_p;
  const u16* __restrict__ QT = flag ? dout : dout + NQ;
  const int t = threadIdx.x;
  const int wave = t >> 6, lane = t & 63;
  const int lr = lane & 15, g = lane >> 4, kg = g * 8;
  const int bh = blockIdx.x;          // fastest grid dim -> XCD = bh % 8
  const int q0 = blockIdx.y * 128;
  const u16* __restrict__ QTh = QT + (size_t)bh * DH * TSEQ;  // [64 d][T]
  const u16* __restrict__ Kh = K + (size_t)bh * TSEQ * DH;
  const u16* __restrict__ Vh = VT + (size_t)bh * DH * TSEQ;

  // Two Q B-fragments per wave (q-sets A/B, 16 q each), gathered from Q^T
  // once per kernel: 32 strided scalar loads.
  const int qiA = q0 + wave * 32 + lr;
  union { u16 s[8]; bf16x8 v; } qa0, qa1, qb0, qb1;
#pragma unroll
  for (int j = 0; j < 8; ++j) {
    qa0.s[j] = QTh[(size_t)(kg + j) * TSEQ + qiA];
    qa1.s[j] = QTh[(size_t)(32 + kg + j) * TSEQ + qiA];
    qb0.s[j] = QTh[(size_t)(kg + j) * TSEQ + qiA + 16];
    qb1.s[j] = QTh[(size_t)(32 + kg + j) * TSEQ + qiA + 16];
  }
  const bf16x8 qfA0 = qa0.v, qfA1 = qa1.v, qfB0 = qb0.v, qfB1 = qb1.v;

  f32x4 accA[4] = {}, accB[4] = {};
  f32x2 lsA0 = {0.f, 0.f}, lsA1 = {0.f, 0.f};
  f32x2 lsB0 = {0.f, 0.f}, lsB1 = {0.f, 0.f};

  const int srow = t >> 2, skc = (t & 3) * 8;
  const u16* kb = Kh + (size_t)srow * DH + skc;
  const u16* vb = Vh + (size_t)srow * TSEQ + skc;
  u16* const pw  = &Ps[wave * 32 * 72];        // q-set A rows 0..15
  u16* const pwB = pw + 16 * 72;               // q-set B rows 16..31

  for (int j0 = 0; j0 < TSEQ; j0 += 64) {
    gl_lds16(kb,      &Ks[t * 8]);          // keys, d 0..31
    gl_lds16(kb + 32, &Ks[(t + 256) * 8]);  // keys, d 32..63
    gl_lds16(vb,      &Vs[t * 8]);          // [d][keys 0..31]
    gl_lds16(vb + 32, &Vs[(t + 256) * 8]);  // [d][keys 32..63]
    kb += 64 * DH; vb += 64;
    __syncthreads();

    // S^T tiles: C col = q (lr), row = key = jn*16 + g*4 + r
#pragma unroll
    for (int jn = 0; jn < 4; ++jn) {
      const bf16x8 kf0 = *(const bf16x8*)&Ks[(jn * 16 + lr) * 32 + kg];
      const bf16x8 kf1 = *(const bf16x8*)&Ks[2048 + (jn * 16 + lr) * 32 + kg];
      f32x4 sA = {}, sB = {};
      sA = __builtin_amdgcn_mfma_f32_16x16x32_bf16(kf0, qfA0, sA, 0, 0, 0);
      sA = __builtin_amdgcn_mfma_f32_16x16x32_bf16(kf1, qfA1, sA, 0, 0, 0);
      sB = __builtin_amdgcn_mfma_f32_16x16x32_bf16(kf0, qfB0, sB, 0, 0, 0);
      sB = __builtin_amdgcn_mfma_f32_16x16x32_bf16(kf1, qfB1, sB, 0, 0, 0);
      const float a0 = __builtin_exp2f(sA[0]);
      const float a1 = __builtin_exp2f(sA[1]);
      const float a2 = __builtin_exp2f(sA[2]);
      const float a3 = __builtin_exp2f(sA[3]);
      const float b0 = __builtin_exp2f(sB[0]);
      const float b1 = __builtin_exp2f(sB[1]);
      const float b2 = __builtin_exp2f(sB[2]);
      const float b3 = __builtin_exp2f(sB[3]);
      lsA0 += (f32x2){a0, a1}; lsA1 += (f32x2){a2, a3};
      lsB0 += (f32x2){b0, b1}; lsB1 += (f32x2){b2, b3};
      uint2 wA, wB;
      wA.x = pack2bf(a0, a1); wA.y = pack2bf(a2, a3);
      wB.x = pack2bf(b0, b1); wB.y = pack2bf(b2, b3);
      *(uint2*)&pw [lr * 72 + jn * 16 + g * 4] = wA;
      *(uint2*)&pwB[lr * 72 + jn * 16 + g * 4] = wB;
    }

    // PV: A = P (m=q), B = V^T rows (n=d). Same-wave DS RAW is in-order.
    const bf16x8 pfA0 = *(const bf16x8*)&pw [lr * 72 + kg];
    const bf16x8 pfA1 = *(const bf16x8*)&pw [lr * 72 + 32 + kg];
    const bf16x8 pfB0 = *(const bf16x8*)&pwB[lr * 72 + kg];
    const bf16x8 pfB1 = *(const bf16x8*)&pwB[lr * 72 + 32 + kg];
#pragma unroll
    for (int dn = 0; dn < 4; ++dn) {
      const bf16x8 vf0 = *(const bf16x8*)&Vs[(dn * 16 + lr) * 32 + kg];
      const bf16x8 vf1 = *(const bf16x8*)&Vs[2048 + (dn * 16 + lr) * 32 + kg];
      accA[dn] = __builtin_amdgcn_mfma_f32_16x16x32_bf16(pfA0, vf0, accA[dn], 0, 0, 0);
      accA[dn] = __builtin_amdgcn_mfma_f32_16x16x32_bf16(pfA1, vf1, accA[dn], 0, 0, 0);
      accB[dn] = __builtin_amdgcn_mfma_f32_16x16x32_bf16(pfB0, vf0, accB[dn], 0, 0, 0);
      accB[dn] = __builtin_amdgcn_mfma_f32_16x16x32_bf16(pfB1, vf1, accB[dn], 0, 0, 0);
    }
    __syncthreads();
  }

  // lsum reductions: lane partial covers key subset for q=lr of each set
  float lA = (lsA0[0] + lsA0[1]) + (lsA1[0] + lsA1[1]);
  lA += __shfl_xor(lA, 16, 64);
  lA += __shfl_xor(lA, 32, 64);
  float lB = (lsB0[0] + lsB0[1]) + (lsB1[0] + lsB1[1]);
  lB += __shfl_xor(lB, 16, 64);
  lB += __shfl_xor(lB, 32, 64);
  Ls[wave * 32 + lr]      = lA;  // same-value multi-write across g, benign
  Ls[wave * 32 + 16 + lr] = lB;
  __syncthreads();

  const int bb = bh >> 4, hh = bh & 15;
#pragma unroll
  for (int r = 0; r < 4; ++r) {
    const int qq = g * 4 + r;
    const float invA = 1.f / fmaxf(Ls[wave * 32 + qq], 1e-30f);
    const float invB = 1.f / fmaxf(Ls[wave * 32 + 16 + qq], 1e-30f);
    const int tiA = q0 + wave * 32 + qq;
    u16* dstA = AO + (((size_t)bb * TSEQ + tiA) * NH + hh) * DH + lr;
    u16* dstB = AO + (((size_t)bb * TSEQ + tiA + 16) * NH + hh) * DH + lr;
#pragma unroll
    for (int dn = 0; dn < 4; ++dn) {
      dstA[dn * 16] = f2bf(accA[dn][r] * invA);
      dstB[dn * 16] = f2bf(accB[dn][r] * invB);
    }
  }
}

// ---------------------------------------------------------------------------
// Kernel 3: output projection  out = AO @ Wo^T + bo  (BK=64 two-buffer).
// ---------------------------------------------------------------------------
__global__ __launch_bounds__(256) void out_gemm(
    const int* __restrict__ flag_p,
    const u16* __restrict__ A, const u16* __restrict__ W,
    const void* __restrict__ bias_raw, void* __restrict__ outp)
{
  __shared__ __align__(16) u16 As[2 * 128 * 32];
  __shared__ __align__(16) u16 Bs[2 * 128 * 32];
  const int flag = *flag_p;
  const int t = threadIdx.x;
  const int m0 = blockIdx.x * 128;
  const int n0 = blockIdx.y * 128;
  const int wave = t >> 6, lane = t & 63;
  const int wm = (wave >> 1) * 64, wn = (wave & 1) * 64;
  const int lr = lane & 15, kg = (lane >> 4) * 8;

  const int srow0 = t >> 2, skc = (t & 3) * 8;
  const int srow1 = srow0 + 64;
  const u16* a0 = A + (size_t)(m0 + srow0) * D_MODEL + skc;
  const u16* a1 = A + (size_t)(m0 + srow1) * D_MODEL + skc;
  const u16* b0 = W + (size_t)(n0 + srow0) * D_MODEL + skc;
  const u16* b1 = W + (size_t)(n0 + srow1) * D_MODEL + skc;

  f32x4 acc[4][4] = {};

  for (int kt = 0; kt < D_MODEL / 64; ++kt) {
    gl_lds16(a0,      &As[t * 8]);
    gl_lds16(a1,      &As[(t + 256) * 8]);
    gl_lds16(a0 + 32, &As[4096 + t * 8]);
    gl_lds16(a1 + 32, &As[4096 + (t + 256) * 8]);
    gl_lds16(b0,      &Bs[t * 8]);
    gl_lds16(b1,      &Bs[(t + 256) * 8]);
    gl_lds16(b0 + 32, &Bs[4096 + t * 8]);
    gl_lds16(b1 + 32, &Bs[4096 + (t + 256) * 8]);
    a0 += 64; a1 += 64; b0 += 64; b1 += 64;
    __syncthreads();
#pragma unroll
    for (int h = 0; h < 2; ++h) {
      bf16x8 af[4], bfr[4];
#pragma unroll
      for (int i = 0; i < 4; ++i)
        af[i] = *(const bf16x8*)&As[h * 4096 + (wm + i * 16 + lr) * 32 + kg];
#pragma unroll
      for (int j = 0; j < 4; ++j)
        bfr[j] = *(const bf16x8*)&Bs[h * 4096 + (wn + j * 16 + lr) * 32 + kg];
#pragma unroll
      for (int i = 0; i < 4; ++i)
#pragma unroll
        for (int j = 0; j < 4; ++j)
          acc[i][j] = __builtin_amdgcn_mfma_f32_16x16x32_bf16(af[i], bfr[j], acc[i][j], 0, 0, 0);
    }
    __syncthreads();
  }

#pragma unroll
  for (int j = 0; j < 4; ++j) {
    const int colg = n0 + wn + j * 16 + lr;
    const float bv = flag ? bf2f(((const u16*)bias_raw)[colg])
                          : ((const float*)bias_raw)[colg];
#pragma unroll
    for (int i = 0; i < 4; ++i) {
      const int rowg = m0 + wm + i * 16 + ((lane >> 4) << 2);
      if (flag) {
        u16* dst = (u16*)outp + (size_t)rowg * D_MODEL + colg;
#pragma unroll
        for (int r = 0; r < 4; ++r)
          dst[(size_t)r * D_MODEL] = f2bf(acc[i][j][r] + bv);
      } else {
        float* dst = (float*)outp + (size_t)rowg * D_MODEL + colg;
#pragma unroll
        for (int r = 0; r < 4; ++r)
          dst[(size_t)r * D_MODEL] = acc[i][j][r] + bv;
      }
    }
  }
}

extern "C" void kernel_launch(void* const* d_in, const int* in_sizes, int n_in,
                              void* d_out, int out_size, void* d_ws, size_t ws_size,
                              hipStream_t stream) {
  const void* x  = d_in[0];
  const void* wq = d_in[1];
  const void* wk = d_in[2];
  const void* wv = d_in[3];
  const void* wo = d_in[4];
  const void* bo = d_in[5];
  u16* dout = (u16*)d_out;

  // ws: [flag 16B][Wq][Wk][Wv][Wo bf16, 2MiB ea][K][VT][AO 16MiB ea]
  int* flag = (int*)d_ws;
  u16* wqb = (u16*)d_ws + 8;
  u16* wkb = wqb + WSZ;
  u16* wvb = wkb + WSZ;
  u16* wob = wvb + WSZ;
  u16* kk  = wob + WSZ;
  u16* vt  = kk + NQ;
  u16* ao  = vt + NQ;

  detect_dtype<<<1, 256, 0, stream>>>((const u32*)wq, flag);

  dim3 gc(NQ / (256 * 8), 5);
  convert_inputs<<<gc, dim3(256), 0, stream>>>(
      x, wq, wk, wv, wo, dout, wqb, wkb, wvb, wob, flag);

  dim3 g1(MTOT / 128, D_MODEL / 128, 3);
  qkv_gemm<<<g1, dim3(256), 0, stream>>>(
      flag, (const u16*)x, dout, wqb, wkb, wvb, kk, vt);

  dim3 g2(BATCH * NH, TSEQ / 128, 1);
  flash_attn<<<g2, dim3(256), 0, stream>>>(flag, dout, kk, vt, ao);

  dim3 g3(MTOT / 128, D_MODEL / 128, 1);
  out_gemm<<<g3, dim3(256), 0, stream>>>(flag, ao, wob, bo, d_out);
}